// Round 8
// baseline (3838.187 us; speedup 1.0000x reference)
//
#include <hip/hip_runtime.h>
#include <hip/hip_bf16.h>
#include <stdint.h>

typedef __attribute__((ext_vector_type(8))) short   short8;
typedef __attribute__((ext_vector_type(8))) __bf16  bf16x8;
typedef __attribute__((ext_vector_type(4))) float   f32x4;

#define DEV __device__ __forceinline__

DEV float bf2f(uint16_t u){ union{uint32_t i; float f;} v; v.i = ((uint32_t)u)<<16; return v.f; }
DEV uint16_t f2bf(float f){
  union{ __hip_bfloat16 b; uint16_t u; } v; v.b = __float2bfloat16(f); return v.u;  // hw cvt, RNE
}
DEV float sigmf(float x){ return 1.0f/(1.0f + __expf(-x)); }
// overflow-safe 5-op tanh: x->-inf => e=inf => 2/(1+inf)-1 = -1; x->+inf => e=0 => +1
DEV float tanhx(float x){ float e = __expf(-2.0f*x); return 2.0f/(1.0f+e) - 1.0f; }

DEV bf16x8 as_bf(short8 s){ union{ short8 s; bf16x8 b; } u; u.s = s; return u.b; }
DEV f32x4 mfma16(short8 a, short8 b, f32x4 c){
  return __builtin_amdgcn_mfma_f32_16x16x32_bf16(as_bf(a), as_bf(b), c, 0, 0, 0);
}
DEV f32x4 vzero(){ f32x4 v; v[0]=0.f; v[1]=0.f; v[2]=0.f; v[3]=0.f; return v; }

// async global->LDS, 16B per lane (dest = wave-uniform base + lane*16)
DEV void gload16(const uint16_t* g, uint16_t* l){
  __builtin_amdgcn_global_load_lds((const __attribute__((address_space(1))) void*)g,
                                   (__attribute__((address_space(3))) void*)l, 16, 0, 0);
}

// ---------------- small prep kernels ----------------
__global__ void cast_bf16_kernel(const float* __restrict__ in, uint16_t* __restrict__ out, int n){
  int i = blockIdx.x*256 + threadIdx.x;
  if (i < n) out[i] = f2bf(in[i]);
}

// rows of 128, store with XOR-swizzled 16B chunks (matches LDS strip layout)
__global__ void cast_swz_kernel(const float* __restrict__ in, uint16_t* __restrict__ out, int n){
  int i = blockIdx.x*256 + threadIdx.x;
  if (i < n){
    int k = i & 127, row = i >> 7;
    out[(row<<7) + (((k>>3) ^ (row&15))<<3) + (k&7)] = f2bf(in[i]);
  }
}

__global__ void xpad_kernel(const float* __restrict__ x, uint16_t* __restrict__ xb, int rows){
  int i = blockIdx.x*256 + threadIdx.x;
  if (i < rows*384){
    int r = i/384, c = i - r*384;
    xb[i] = (c < 369) ? f2bf(x[r*369 + c]) : (uint16_t)0;
  }
}

__global__ void lwt_kernel(const float* __restrict__ lw, uint16_t* __restrict__ lwT){
  int i = blockIdx.x*256 + threadIdx.x;   // out [128][384]: lwT[n][k] = lin_w[k][n]
  if (i < 128*384){
    int nn = i/384, k = i - nn*384;
    lwT[i] = (k < 369) ? f2bf(lw[k*128 + nn]) : (uint16_t)0;
  }
}

// bias4[t][c] = {bih[c]+bhh[c], bih[128+c]+bhh[128+c], bih[256+c], bhh[256+c]}
__global__ void bias4_kernel(const float* __restrict__ bih, const float* __restrict__ bhh,
                             float4* __restrict__ b4, int TT){
  int i = blockIdx.x*256 + threadIdx.x;
  if (i < TT*128){
    int t = i >> 7, c = i & 127;
    const float* A = bih + t*384; const float* B = bhh + t*384;
    b4[i] = make_float4(A[c]+B[c], A[128+c]+B[128+c], A[256+c], B[256+c]);
  }
}

// ---------------- generic bf16 gemm: C[m][n] = sum_k A[m][k]*B[n][k] (+bias[n]) ----------------
__global__ __launch_bounds__(256,2)
void gemm_bt_kernel(const uint16_t* __restrict__ A, const uint16_t* __restrict__ B,
                    uint16_t* __restrict__ C,
                    int lda, int ldb, int M, int K4,
                    const float* __restrict__ bias, int swz,
                    long sA, long sB, long sC, int divA)
{
  int by = blockIdx.y;
  A += (long)(by/divA)*sA; B += (long)by*sB; C += (long)by*sC;
  int tid = threadIdx.x, lane = tid&63, wave = tid>>6;
  int l15 = lane&15, quad = lane>>4;
  int m0 = blockIdx.x*64 + wave*16;
  f32x4 acc[8];
  #pragma unroll
  for (int nf=0; nf<8; ++nf) acc[nf] = vzero();
  int mrow = min(m0 + l15, M-1);
  const char* arow = (const char*)(A + (long)mrow*lda) + quad*16;
  for (int kk=0; kk<K4; ++kk){
    short8 a = *(const short8*)(arow + kk*64);
    #pragma unroll
    for (int nf=0; nf<8; ++nf){
      const char* brow = (const char*)(B + (long)(nf*16+l15)*ldb) + quad*16;
      short8 b = *(const short8*)(brow + kk*64);
      acc[nf] = mfma16(a, b, acc[nf]);
    }
  }
  #pragma unroll
  for (int nf=0; nf<8; ++nf){
    int col = nf*16 + l15;
    float bb = bias ? bias[col] : 0.0f;
    #pragma unroll
    for (int i=0; i<4; ++i){
      int row = m0 + quad*4 + i;
      if (row < M){
        float v = acc[nf][i] + bb;
        int idx = swz ? (row*128 + (((col>>3)^(row&15))<<3) + (col&7)) : (row*128+col);
        C[idx] = f2bf(v);
      }
    }
  }
}

// ---------------- CSR build ----------------
__global__ void edge_count_kernel(const int* __restrict__ ei, const int* __restrict__ ea,
                                  int* __restrict__ cnt, int E, int n){
  int e = blockIdx.x*256 + threadIdx.x;
  if (e < E){
    int dst = ei[E + e];
    int t = ea[e];
    atomicAdd(&cnt[t*n + dst], 1);
  }
}

__global__ void csr_alloc_kernel(const int* __restrict__ cnt, int* __restrict__ row_start,
                                 int* __restrict__ cursor, int* __restrict__ total, int R){
  __shared__ int wsum[4];
  __shared__ int base;
  int i = blockIdx.x*256 + threadIdx.x;
  int c = (i < R) ? cnt[i] : 0;
  int lane = threadIdx.x & 63, wave = threadIdx.x >> 6;
  int x = c;
  #pragma unroll
  for (int d=1; d<64; d<<=1){ int y = __shfl_up(x, d, 64); if (lane >= d) x += y; }
  if (lane == 63) wsum[wave] = x;
  __syncthreads();
  if (threadIdx.x == 0){
    int s0=wsum[0], s1=wsum[1], s2=wsum[2], s3=wsum[3];
    base = atomicAdd(total, s0+s1+s2+s3);
    wsum[0]=0; wsum[1]=s0; wsum[2]=s0+s1; wsum[3]=s0+s1+s2;
  }
  __syncthreads();
  int st = base + wsum[wave] + (x - c);
  if (i < R){ row_start[i] = st; cursor[i] = st; }
}

__global__ void edge_fill_kernel(const int* __restrict__ ei, const int* __restrict__ ea,
                                 int* __restrict__ cursor, int* __restrict__ csr, int E, int n){
  int e = blockIdx.x*256 + threadIdx.x;
  if (e < E){
    int src = ei[e], dst = ei[E+e], t = ea[e];
    int pos = atomicAdd(&cursor[t*n + dst], 1);
    csr[pos] = src;
  }
}

// ---------------- Pass A: aggregation (pure gather, high occupancy) ----------------
// thread = (row, 8-col chunk); 16 threads cover a 128-col row (256B coalesced per edge)
__global__ void agg_kernel(const uint16_t* __restrict__ h_in_b,
                           uint16_t* __restrict__ agg_b,
                           const int* __restrict__ row_start_b,
                           const int* __restrict__ row_cnt_b,
                           const int* __restrict__ csr_src,
                           int n, int t_off, long hin_stride)
{
  const int t = t_off + blockIdx.y;
  const uint16_t* h_in = h_in_b + (long)blockIdx.y*hin_stride;
  uint16_t* agg = agg_b + (long)blockIdx.y*((long)n*128);
  int id = blockIdx.x*256 + threadIdx.x;
  int row = id >> 4, c = (id & 15) * 8;
  if (row < n){
    int st = row_start_b[(size_t)t*n + row];
    int cn = row_cnt_b  [(size_t)t*n + row];
    float acc[8] = {0,0,0,0,0,0,0,0};
    for (int e=0; e<cn; ++e){
      int src = csr_src[st + e];
      short8 v = *(const short8*)(h_in + (long)src*128 + c);
      #pragma unroll
      for (int j=0; j<8; ++j) acc[j] += bf2f((uint16_t)v[j]);
    }
    short8 pk;
    #pragma unroll
    for (int j=0; j<8; ++j) pk[j] = (short)f2bf(acc[j]);
    *(short8*)(agg + (long)row*128 + c) = pk;
  }
}

// ---------------- Pass B: dense GEMM + GRU (R3 structure, VALU-trimmed) ----------------
// Block = 128 rows x 128 cols of one edge-type; 512 thr / 8 waves; 2 blocks/CU (64 KB LDS).
// EXACT R3 structure (best measured: 170us/dispatch, 268MB/pair). Only deltas vs R3:
//   - bias4 float4 table replaces 6 scalar bias loads+adds per nf (pure VALU/SMEM trim)
//   - tanhx branch-free (drops 2 clamp ops)
// Epilogue: 2B scatter + in-place h reread, UNCHANGED — R7 proved L2 merges this near-
// optimally (120MB writes); "coalescing fixes" (R6/R7) exploded traffic to 344-443MB.
// In-place safe: block touches only its own rows.
__global__ __launch_bounds__(512, 4)
void ggnn_step_kernel(const uint16_t* __restrict__ h_in_b,
                      const uint16_t* __restrict__ agg_b,
                      uint16_t* __restrict__ h_out_b,
                      const uint16_t* __restrict__ W1_b,   // [T*8][384][128] swizzled
                      const uint16_t* __restrict__ W2_b,   // [T][384][128] swizzled
                      const float4* __restrict__ bias4_b,  // [T][128] {br,bz,bin,bhn}
                      int n, int s, int t_off,
                      long hin_stride, long hstride)
{
  __shared__ __align__(16) uint16_t sB[2][128*128];    // 2 x 32 KB strips
  const int t = t_off + blockIdx.y;
  const uint16_t* h_in = h_in_b + (long)blockIdx.y*hin_stride;
  const uint16_t* agg  = agg_b  + (long)blockIdx.y*hstride;
  uint16_t*       h_out= h_out_b+ (long)blockIdx.y*hstride;
  const uint16_t* W1s = W1_b + (size_t)(t*8+s)*384*128;
  const uint16_t* W2s = W2_b + (size_t)t*384*128;
  const float4*   b4p = bias4_b + t*128;

  const int tid = threadIdx.x, lane = tid&63, wave = tid>>6;   // 8 waves
  const int l15 = lane&15, quad = lane>>4;
  const int rbase = blockIdx.x*128;

  // strips in use order: rW1, rW2, nW2, nW1, zW1, zW2 (torch rows: r=0..127, z=128..255, n=256..383)
  const uint16_t* stp[6] = { W1s, W2s, W2s+2*16384, W1s+2*16384, W1s+16384, W2s+16384 };

  // ---- stage strip 0 into buf 0 (DMA; 512 thr x 16B x 4 rounds = 32KB) ----
  {
    const uint16_t* gp = stp[0] + tid*8;
    uint16_t* lp = &sB[0][tid*8];
    #pragma unroll
    for (int it=0; it<4; ++it) gload16(gp + it*4096, lp + it*4096);
  }

  // ---- A-fragments: h (used 3x) and agg (used 3x) ----
  const int ar = min(rbase + wave*16 + l15, n-1);
  short8 hfr[4], afr[4];
  {
    const short8* hrow = (const short8*)(h_in + (long)ar*128);
    const short8* arow = (const short8*)(agg  + (long)ar*128);
    #pragma unroll
    for (int kk=0; kk<4; ++kk){ hfr[kk] = hrow[kk*4 + quad]; afr[kk] = arow[kk*4 + quad]; }
  }

  // ---- per-lane bias table (8 x float4 in regs) ----
  float4 b4[8];
  #pragma unroll
  for (int nf=0; nf<8; ++nf) b4[nf] = b4p[nf*16 + l15];

  auto mma = [&](const uint16_t* bufp, f32x4 (&acc)[8], const short8 (&frag)[4]){
    #pragma unroll
    for (int kk=0; kk<4; ++kk){
      const int ch = ((kk*4+quad)^l15)<<4;
      short8 a = frag[kk];
      #pragma unroll
      for (int nf=0; nf<8; ++nf){
        short8 b = *(const short8*)((const char*)bufp + (nf*16+l15)*256 + ch);
        acc[nf] = mfma16(a, b, acc[nf]);
      }
    }
  };

  f32x4 rg[8], nn[8];
  #pragma unroll
  for (int nf=0; nf<8; ++nf){ rg[nf]=vzero(); nn[nf]=vzero(); }

  // ---- 6 strips: fenced DMA issue + counted vmcnt, raw barriers, mma + gate math ----
  #pragma unroll
  for (int g=0; g<6; ++g){
    if (g < 5){
      __builtin_amdgcn_sched_barrier(0);                 // fence the DMA issue window
      const uint16_t* gp = stp[g+1] + tid*8;
      uint16_t* lp = &sB[(g+1)&1][tid*8];
      #pragma unroll
      for (int it=0; it<4; ++it) gload16(gp + it*4096, lp + it*4096);
      asm volatile("s_waitcnt vmcnt(4)" ::: "memory");   // only strip g+1's 4 DMAs may remain
      __builtin_amdgcn_sched_barrier(0);
    } else {
      asm volatile("s_waitcnt vmcnt(0)" ::: "memory");
    }
    __builtin_amdgcn_s_barrier();                        // strip g visible to all waves

    const uint16_t* bufp = sB[g&1];
    if (g == 0)      mma(bufp, rg, afr);                 // r += agg@W1r
    else if (g == 1){
      mma(bufp, rg, hfr);                                // r += h@W2r
      #pragma unroll
      for (int nf=0; nf<8; ++nf){
        float bs = b4[nf].x;
        #pragma unroll
        for (int i=0; i<4; ++i) rg[nf][i] = sigmf(rg[nf][i] + bs);
      }
    }
    else if (g == 2){
      mma(bufp, nn, hfr);                                // nn = h@W2n
      #pragma unroll
      for (int nf=0; nf<8; ++nf){
        float bin = b4[nf].z, bhn = b4[nf].w;
        #pragma unroll
        for (int i=0; i<4; ++i)
          nn[nf][i] = bin + rg[nf][i]*(nn[nf][i] + bhn); // pre-accumulate form
        rg[nf] = vzero();                                // rg reused as z accumulator
      }
    }
    else if (g == 3){
      mma(bufp, nn, afr);                                // nn += agg@W1n
      #pragma unroll
      for (int nf=0; nf<8; ++nf)
        #pragma unroll
        for (int i=0; i<4; ++i) nn[nf][i] = tanhx(nn[nf][i]);
    }
    else if (g == 4) mma(bufp, rg, afr);                 // z += agg@W1z
    else             mma(bufp, rg, hfr);                 // z += h@W2z

    __builtin_amdgcn_s_barrier();                        // all waves done reading buf g&1
  }

  // ---- combine + direct C-layout writeout (R3 epilogue: L2 merges the 2B scatter) ----
  #pragma unroll
  for (int nf=0; nf<8; ++nf){
    int col = nf*16 + l15;
    float bs = b4[nf].y;
    #pragma unroll
    for (int i=0; i<4; ++i){
      int row = rbase + wave*16 + quad*4 + i;
      if (row < n){
        float z = sigmf(rg[nf][i] + bs);
        float hv = bf2f(h_in[(long)row*128 + col]);
        float hnew = nn[nf][i] + z*(hv - nn[nf][i]);
        h_out[(long)row*128 + col] = f2bf(hnew);
      }
    }
  }
}

// ---------------- reduce final per-type h into messages ----------------
__global__ void reduce_kernel(const uint16_t* __restrict__ hfin, float* __restrict__ messages,
                              long stride, int nt, int accumulate, int total8){
  int i = blockIdx.x*256 + threadIdx.x;   // units of 8 elements
  if (i < total8){
    float acc[8];
    #pragma unroll
    for (int j=0;j<8;++j) acc[j] = 0.f;
    if (accumulate){
      #pragma unroll
      for (int j=0;j<8;++j) acc[j] = messages[(long)i*8 + j];
    }
    for (int t=0; t<nt; ++t){
      short8 v = *(const short8*)(hfin + (long)t*stride + (long)i*8);
      #pragma unroll
      for (int j=0;j<8;++j) acc[j] += bf2f((uint16_t)v[j]);
    }
    #pragma unroll
    for (int j=0;j<8;++j) messages[(long)i*8 + j] = acc[j];
  }
}

// ---------------- pooling + classifier ----------------
__global__ void pool_kernel(const float* __restrict__ messages, const int* __restrict__ batch,
                            float* __restrict__ sums, int* __restrict__ cntg, int n){
  int id = blockIdx.x*256 + threadIdx.x;
  int col = id & 127;
  int nb = (id >> 7) * 8;
  float acc = 0.f; int curg = -1; int ccount = 0;
  for (int j=0; j<8; ++j){
    int node = nb + j;
    if (node < n){
      int g = batch[node];
      if (g != curg){
        if (curg >= 0){
          atomicAdd(&sums[curg*128+col], acc);
          if (col == 0) atomicAdd(&cntg[curg], ccount);
        }
        curg = g; acc = 0.f; ccount = 0;
      }
      acc += messages[(long)node*128 + col];
      ccount++;
    }
  }
  if (curg >= 0){
    atomicAdd(&sums[curg*128+col], acc);
    if (col == 0) atomicAdd(&cntg[curg], ccount);
  }
}

__global__ void classify_kernel(const float* __restrict__ sums, const int* __restrict__ cntg,
                                const float* __restrict__ cls_w, const float* __restrict__ cls_b,
                                float* __restrict__ out, int G){
  int g = threadIdx.x;
  if (g < G){
    float inv = 1.0f / fmaxf((float)cntg[g], 1.0f);
    float o0 = 0.f, o1 = 0.f;
    for (int d=0; d<128; ++d){
      float p = sums[g*128+d]*inv;
      o0 += p*cls_w[d*2];
      o1 += p*cls_w[d*2+1];
    }
    out[g*2]   = o0 + cls_b[0];
    out[g*2+1] = o1 + cls_b[1];
  }
}

extern "C" void kernel_launch(void* const* d_in, const int* in_sizes, int n_in,
                              void* d_out, int out_size, void* d_ws, size_t ws_size,
                              hipStream_t stream)
{
  const float* x      = (const float*)d_in[0];
  const int*   ei     = (const int*)d_in[1];
  const int*   ea     = (const int*)d_in[2];
  const int*   batch  = (const int*)d_in[3];
  const float* lin_w  = (const float*)d_in[4];
  const float* lin_b  = (const float*)d_in[5];
  const float* ggnn_w = (const float*)d_in[6];
  const float* w_ih   = (const float*)d_in[7];
  const float* w_hh   = (const float*)d_in[8];
  const float* b_ih   = (const float*)d_in[9];
  const float* b_hh   = (const float*)d_in[10];
  const float* cls_w  = (const float*)d_in[11];
  const float* cls_b  = (const float*)d_in[12];
  float* out = (float*)d_out;

  const int N = in_sizes[3];          // 50000 nodes
  const int E = in_sizes[2];          // 800000 edges
  const int T = in_sizes[9] / 384;    // 13 edge types
  const int G = out_size / 2;         // 256 graphs
  const int STEPS = 8;

  // ---- workspace: persistent block + overlap region (prep buffers alias hT/agg) ----
  struct Layout {
    float *messages, *sums; int *cntg, *total;
    int *cnt, *row_start, *csr;
    uint16_t *W2t, *W1t, *h0;
    float4 *bias4;
    uint16_t *hT, *agg;
    int *cursor; uint16_t *xb, *lwT, *gwb, *wihb;
    size_t zero_off, zero_len, end;
  };
  auto make_layout = [&](int nh)->Layout{
    Layout L; char* base = (char*)d_ws; char* p = base;
    auto A = [&](size_t b)->char*{ char* r = p; p += (b + 255) & ~(size_t)255; return r; };
    L.messages  = (float*)A((size_t)N*128*4);
    char* z0 = p;
    L.sums      = (float*)A((size_t)G*128*4);
    L.cntg      = (int*)  A((size_t)G*4);
    L.total     = (int*)  A(256);
    L.zero_off = (size_t)(z0 - base); L.zero_len = (size_t)(p - z0);
    L.cnt       = (int*)  A((size_t)T*N*4);
    L.row_start = (int*)  A((size_t)T*N*4);
    L.csr       = (int*)  A((size_t)E*4);
    L.W2t       = (uint16_t*)A((size_t)T*384*128*2);
    L.W1t       = (uint16_t*)A((size_t)T*8*384*128*2);
    L.h0        = (uint16_t*)A((size_t)N*128*2);
    L.bias4     = (float4*)  A((size_t)T*128*16);
    // overlap region: [hT | agg] || prep-only buffers
    char* R = p;
    size_t hb  = (size_t)N*128*2;
    size_t hba = ((size_t)nh*hb + 255) & ~(size_t)255;
    L.hT = (uint16_t*)R; L.agg = (uint16_t*)(R + hba);
    size_t hreg = 2*hba;
    char* q = R;
    auto B = [&](size_t b)->char*{ char* r = q; q += (b + 255) & ~(size_t)255; return r; };
    L.cursor = (int*)     B((size_t)T*N*4);
    L.xb     = (uint16_t*)B((size_t)N*384*2);
    L.lwT    = (uint16_t*)B((size_t)128*384*2);
    L.gwb    = (uint16_t*)B((size_t)T*8*128*128*2);
    L.wihb   = (uint16_t*)B((size_t)T*384*128*2);
    size_t preg = (size_t)(q - R);
    L.end = (size_t)(R - base) + (hreg > preg ? hreg : preg);
    return L;
  };
  // in-place h: R3's proven grouping (nh=7 -> groups of 7+6)
  int nh = 1;
  { int cand[6] = {7, 6, 5, 4, 3, 2};
    for (int i=0; i<6; ++i){
      int c = cand[i] < T ? cand[i] : T;
      if (make_layout(c).end <= ws_size){ nh = c; break; }
    } }
  Layout L = make_layout(nh);

  hipMemsetAsync((char*)d_ws + L.zero_off, 0, L.zero_len, stream);   // sums/cntg/total
  hipMemsetAsync(L.cnt, 0, (size_t)T*N*4, stream);

  const int ngw = T*8*128*128, nwih = T*384*128;
  cast_bf16_kernel<<<(ngw+255)/256, 256, 0, stream>>>(ggnn_w, L.gwb, ngw);
  cast_bf16_kernel<<<(nwih+255)/256, 256, 0, stream>>>(w_ih, L.wihb, nwih);
  cast_swz_kernel <<<(nwih+255)/256, 256, 0, stream>>>(w_hh, L.W2t, nwih);
  xpad_kernel<<<((N*384)+255)/256, 256, 0, stream>>>(x, L.xb, N);
  lwt_kernel<<<(128*384+255)/256, 256, 0, stream>>>(lin_w, L.lwT);
  bias4_kernel<<<(T*128+255)/256, 256, 0, stream>>>(b_ih, b_hh, L.bias4, T);

  // W1t[t*8+s][j][k] = sum_d w_ih[t][j][d] * ggnn_w[t][s][k][d]  (swizzled store)
  gemm_bt_kernel<<<dim3(6, T*8), 256, 0, stream>>>(L.wihb, L.gwb, L.W1t, 128, 128, 384, 4,
      nullptr, 1, (long)384*128, (long)128*128, (long)384*128, 8);
  // h0 = xb @ lwT^T + lin_b   (plain store)
  gemm_bt_kernel<<<dim3((N+63)/64, 1), 256, 0, stream>>>(L.xb, L.lwT, L.h0, 384, 384, N, 12,
      lin_b, 0, 0, 0, 0, 1);

  edge_count_kernel<<<(E+255)/256, 256, 0, stream>>>(ei, ea, L.cnt, E, N);
  csr_alloc_kernel <<<(T*N+255)/256, 256, 0, stream>>>(L.cnt, L.row_start, L.cursor, L.total, T*N);
  edge_fill_kernel <<<(E+255)/256, 256, 0, stream>>>(ei, ea, L.cursor, L.csr, E, N);

  const int nblk = (N+127)/128;
  const int ablk = (N*16 + 255)/256;
  const long hs = (long)N*128;
  const int total8 = N*128/8;
  const int ngroups = (T + nh - 1)/nh;

  for (int gidx=0; gidx<ngroups; ++gidx){
    int t0 = gidx*nh, nt = (T - t0 < nh) ? (T - t0) : nh;
    for (int s=0; s<STEPS; ++s){
      const uint16_t* hin = (s==0) ? L.h0 : L.hT;
      long hin_stride = (s==0) ? 0 : hs;
      // Pass A: gather into agg (bandwidth-bound, high occupancy)
      agg_kernel<<<dim3(ablk, nt), 256, 0, stream>>>(
          hin, L.agg, L.row_start, L.cnt, L.csr, N, t0, hin_stride);
      // Pass B: dense dual-GEMM + GRU; writes hT (in place for s>=1)
      ggnn_step_kernel<<<dim3(nblk, nt), 512, 0, stream>>>(
          hin, L.agg, L.hT, L.W1t, L.W2t, L.bias4,
          N, s, t0, hin_stride, hs);
    }
    // fold this group's final h into messages
    reduce_kernel<<<(total8+255)/256, 256, 0, stream>>>(L.hT, L.messages, hs, nt,
                                                        (gidx>0) ? 1 : 0, total8);
  }

  pool_kernel<<<((N*128)+2047)/2048, 256, 0, stream>>>(L.messages, batch, L.sums, L.cntg, N);
  classify_kernel<<<1, 256, 0, stream>>>(L.sums, L.cntg, cls_w, cls_b, out, G);
}

// Round 9
// 3254.868 us; speedup vs baseline: 1.1792x; 1.1792x over previous
//
#include <hip/hip_runtime.h>
#include <hip/hip_bf16.h>
#include <stdint.h>

typedef __attribute__((ext_vector_type(8))) short   short8;
typedef __attribute__((ext_vector_type(8))) __bf16  bf16x8;
typedef __attribute__((ext_vector_type(4))) float   f32x4;

#define DEV __device__ __forceinline__

DEV float bf2f(uint16_t u){ union{uint32_t i; float f;} v; v.i = ((uint32_t)u)<<16; return v.f; }
DEV uint16_t f2bf(float f){
  union{ __hip_bfloat16 b; uint16_t u; } v; v.b = __float2bfloat16(f); return v.u;  // hw cvt, RNE
}
DEV float sigmf(float x){ return 1.0f/(1.0f + __expf(-x)); }
DEV float tanhx(float x){ x = fminf(15.f, fmaxf(-15.f, x)); float e = __expf(-2.0f*x);
  return (1.0f-e)/(1.0f+e); }

DEV bf16x8 as_bf(short8 s){ union{ short8 s; bf16x8 b; } u; u.s = s; return u.b; }
DEV f32x4 mfma16(short8 a, short8 b, f32x4 c){
  return __builtin_amdgcn_mfma_f32_16x16x32_bf16(as_bf(a), as_bf(b), c, 0, 0, 0);
}
DEV f32x4 vzero(){ f32x4 v; v[0]=0.f; v[1]=0.f; v[2]=0.f; v[3]=0.f; return v; }

// async global->LDS, 16B per lane (dest = wave-uniform base + lane*16)
DEV void gload16(const uint16_t* g, uint16_t* l){
  __builtin_amdgcn_global_load_lds((const __attribute__((address_space(1))) void*)g,
                                   (__attribute__((address_space(3))) void*)l, 16, 0, 0);
}

// ---------------- small prep kernels ----------------
__global__ void cast_bf16_kernel(const float* __restrict__ in, uint16_t* __restrict__ out, int n){
  int i = blockIdx.x*256 + threadIdx.x;
  if (i < n) out[i] = f2bf(in[i]);
}

// rows of 128, store with XOR-swizzled 16B chunks (matches LDS strip layout)
__global__ void cast_swz_kernel(const float* __restrict__ in, uint16_t* __restrict__ out, int n){
  int i = blockIdx.x*256 + threadIdx.x;
  if (i < n){
    int k = i & 127, row = i >> 7;
    out[(row<<7) + (((k>>3) ^ (row&15))<<3) + (k&7)] = f2bf(in[i]);
  }
}

__global__ void xpad_kernel(const float* __restrict__ x, uint16_t* __restrict__ xb, int rows){
  int i = blockIdx.x*256 + threadIdx.x;
  if (i < rows*384){
    int r = i/384, c = i - r*384;
    xb[i] = (c < 369) ? f2bf(x[r*369 + c]) : (uint16_t)0;
  }
}

__global__ void lwt_kernel(const float* __restrict__ lw, uint16_t* __restrict__ lwT){
  int i = blockIdx.x*256 + threadIdx.x;   // out [128][384]: lwT[n][k] = lin_w[k][n]
  if (i < 128*384){
    int nn = i/384, k = i - nn*384;
    lwT[i] = (k < 369) ? f2bf(lw[k*128 + nn]) : (uint16_t)0;
  }
}

// ---------------- generic bf16 gemm: C[m][n] = sum_k A[m][k]*B[n][k] (+bias[n]) ----------------
__global__ __launch_bounds__(256,2)
void gemm_bt_kernel(const uint16_t* __restrict__ A, const uint16_t* __restrict__ B,
                    uint16_t* __restrict__ C,
                    int lda, int ldb, int M, int K4,
                    const float* __restrict__ bias, int swz,
                    long sA, long sB, long sC, int divA)
{
  int by = blockIdx.y;
  A += (long)(by/divA)*sA; B += (long)by*sB; C += (long)by*sC;
  int tid = threadIdx.x, lane = tid&63, wave = tid>>6;
  int l15 = lane&15, quad = lane>>4;
  int m0 = blockIdx.x*64 + wave*16;
  f32x4 acc[8];
  #pragma unroll
  for (int nf=0; nf<8; ++nf) acc[nf] = vzero();
  int mrow = min(m0 + l15, M-1);
  const char* arow = (const char*)(A + (long)mrow*lda) + quad*16;
  for (int kk=0; kk<K4; ++kk){
    short8 a = *(const short8*)(arow + kk*64);
    #pragma unroll
    for (int nf=0; nf<8; ++nf){
      const char* brow = (const char*)(B + (long)(nf*16+l15)*ldb) + quad*16;
      short8 b = *(const short8*)(brow + kk*64);
      acc[nf] = mfma16(a, b, acc[nf]);
    }
  }
  #pragma unroll
  for (int nf=0; nf<8; ++nf){
    int col = nf*16 + l15;
    float bb = bias ? bias[col] : 0.0f;
    #pragma unroll
    for (int i=0; i<4; ++i){
      int row = m0 + quad*4 + i;
      if (row < M){
        float v = acc[nf][i] + bb;
        int idx = swz ? (row*128 + (((col>>3)^(row&15))<<3) + (col&7)) : (row*128+col);
        C[idx] = f2bf(v);
      }
    }
  }
}

// ---------------- CSR build ----------------
__global__ void edge_count_kernel(const int* __restrict__ ei, const int* __restrict__ ea,
                                  int* __restrict__ cnt, int E, int n){
  int e = blockIdx.x*256 + threadIdx.x;
  if (e < E){
    int dst = ei[E + e];
    int t = ea[e];
    atomicAdd(&cnt[t*n + dst], 1);
  }
}

__global__ void csr_alloc_kernel(const int* __restrict__ cnt, int* __restrict__ row_start,
                                 int* __restrict__ cursor, int* __restrict__ total, int R){
  __shared__ int wsum[4];
  __shared__ int base;
  int i = blockIdx.x*256 + threadIdx.x;
  int c = (i < R) ? cnt[i] : 0;
  int lane = threadIdx.x & 63, wave = threadIdx.x >> 6;
  int x = c;
  #pragma unroll
  for (int d=1; d<64; d<<=1){ int y = __shfl_up(x, d, 64); if (lane >= d) x += y; }
  if (lane == 63) wsum[wave] = x;
  __syncthreads();
  if (threadIdx.x == 0){
    int s0=wsum[0], s1=wsum[1], s2=wsum[2], s3=wsum[3];
    base = atomicAdd(total, s0+s1+s2+s3);
    wsum[0]=0; wsum[1]=s0; wsum[2]=s0+s1; wsum[3]=s0+s1+s2;
  }
  __syncthreads();
  int st = base + wsum[wave] + (x - c);
  if (i < R){ row_start[i] = st; cursor[i] = st; }
}

__global__ void edge_fill_kernel(const int* __restrict__ ei, const int* __restrict__ ea,
                                 int* __restrict__ cursor, int* __restrict__ csr, int E, int n){
  int e = blockIdx.x*256 + threadIdx.x;
  if (e < E){
    int src = ei[e], dst = ei[E+e], t = ea[e];
    int pos = atomicAdd(&cursor[t*n + dst], 1);
    csr[pos] = src;
  }
}

// ---------------- Pass A: aggregation (pure gather, high occupancy) ----------------
// thread = (row, 8-col chunk); 16 threads cover a 128-col row (256B coalesced per edge)
__global__ void agg_kernel(const uint16_t* __restrict__ h_in_b,
                           uint16_t* __restrict__ agg_b,
                           const int* __restrict__ row_start_b,
                           const int* __restrict__ row_cnt_b,
                           const int* __restrict__ csr_src,
                           int n, int t_off, long hin_stride)
{
  const int t = t_off + blockIdx.y;
  const uint16_t* h_in = h_in_b + (long)blockIdx.y*hin_stride;
  uint16_t* agg = agg_b + (long)blockIdx.y*((long)n*128);
  int id = blockIdx.x*256 + threadIdx.x;
  int row = id >> 4, c = (id & 15) * 8;
  if (row < n){
    int st = row_start_b[(size_t)t*n + row];
    int cn = row_cnt_b  [(size_t)t*n + row];
    float acc[8] = {0,0,0,0,0,0,0,0};
    for (int e=0; e<cn; ++e){
      int src = csr_src[st + e];
      short8 v = *(const short8*)(h_in + (long)src*128 + c);
      #pragma unroll
      for (int j=0; j<8; ++j) acc[j] += bf2f((uint16_t)v[j]);
    }
    short8 pk;
    #pragma unroll
    for (int j=0; j<8; ++j) pk[j] = (short)f2bf(acc[j]);
    *(short8*)(agg + (long)row*128 + c) = pk;
  }
}

// ---------------- Pass B: dense GEMM + GRU (v3: 512thr / 8 waves / 128 rows) ----------------
// Block = 128 rows x 128 cols of one edge-type; wave = 16 rows x 128 cols (VGPR 64 + AGPR acc).
// 2 blocks/CU (LDS 2x32KB dbuf); reg file caps occupancy at ~4 waves/SIMD (structural).
// Weights staged by global_load_lds, counted vmcnt(4). In-place safe: own rows only.
// [R8->R9: byte-identical revert to the R3 source that measured 3246us. Controlled A/B vs
//  R8 (bias4+tanhx, 3838us): isolates whether those trims or environment caused the mode flip.]
__global__ __launch_bounds__(512, 4)
void ggnn_step_kernel(const uint16_t* __restrict__ h_in_b,
                      const uint16_t* __restrict__ agg_b,
                      uint16_t* __restrict__ h_out_b,
                      const uint16_t* __restrict__ W1_b,   // [T*8][384][128] swizzled
                      const uint16_t* __restrict__ W2_b,   // [T][384][128] swizzled
                      const float* __restrict__ bih_b,     // [T][384]
                      const float* __restrict__ bhh_b,     // [T][384]
                      int n, int s, int t_off,
                      long hin_stride, long hstride)
{
  __shared__ __align__(16) uint16_t sB[2][128*128];    // 2 x 32 KB strips
  const int t = t_off + blockIdx.y;
  const uint16_t* h_in = h_in_b + (long)blockIdx.y*hin_stride;
  const uint16_t* agg  = agg_b  + (long)blockIdx.y*hstride;
  uint16_t*       h_out= h_out_b+ (long)blockIdx.y*hstride;
  const uint16_t* W1s = W1_b + (size_t)(t*8+s)*384*128;
  const uint16_t* W2s = W2_b + (size_t)t*384*128;
  const float* bih = bih_b + t*384;
  const float* bhh = bhh_b + t*384;

  const int tid = threadIdx.x, lane = tid&63, wave = tid>>6;   // 8 waves
  const int l15 = lane&15, quad = lane>>4;
  const int rbase = blockIdx.x*128;

  // strips in use order: rW1, rW2, nW2, nW1, zW1, zW2 (torch rows: r=0..127, z=128..255, n=256..383)
  const uint16_t* stp[6] = { W1s, W2s, W2s+2*16384, W1s+2*16384, W1s+16384, W2s+16384 };

  // ---- stage strip 0 into buf 0 (DMA; 512 thr x 16B x 4 rounds = 32KB) ----
  {
    const uint16_t* gp = stp[0] + tid*8;
    uint16_t* lp = &sB[0][tid*8];
    #pragma unroll
    for (int it=0; it<4; ++it) gload16(gp + it*4096, lp + it*4096);
  }

  // ---- A-fragments: h (used 3x) and agg (used 3x) ----
  const int ar = min(rbase + wave*16 + l15, n-1);
  short8 hfr[4], afr[4];
  {
    const short8* hrow = (const short8*)(h_in + (long)ar*128);
    const short8* arow = (const short8*)(agg  + (long)ar*128);
    #pragma unroll
    for (int kk=0; kk<4; ++kk){ hfr[kk] = hrow[kk*4 + quad]; afr[kk] = arow[kk*4 + quad]; }
  }

  auto mma = [&](const uint16_t* bufp, f32x4 (&acc)[8], const short8 (&frag)[4]){
    #pragma unroll
    for (int kk=0; kk<4; ++kk){
      const int ch = ((kk*4+quad)^l15)<<4;
      short8 a = frag[kk];
      #pragma unroll
      for (int nf=0; nf<8; ++nf){
        short8 b = *(const short8*)((const char*)bufp + (nf*16+l15)*256 + ch);
        acc[nf] = mfma16(a, b, acc[nf]);
      }
    }
  };

  f32x4 rg[8], nn[8];
  #pragma unroll
  for (int nf=0; nf<8; ++nf){ rg[nf]=vzero(); nn[nf]=vzero(); }

  // ---- 6 strips: fenced DMA issue + counted vmcnt, raw barriers, mma + gate math ----
  #pragma unroll
  for (int g=0; g<6; ++g){
    if (g < 5){
      __builtin_amdgcn_sched_barrier(0);                 // fence: only the 4 DMAs in this window
      const uint16_t* gp = stp[g+1] + tid*8;
      uint16_t* lp = &sB[(g+1)&1][tid*8];
      #pragma unroll
      for (int it=0; it<4; ++it) gload16(gp + it*4096, lp + it*4096);
      asm volatile("s_waitcnt vmcnt(4)" ::: "memory");   // strip g drained; g+1 stays in flight
      __builtin_amdgcn_sched_barrier(0);
    } else {
      asm volatile("s_waitcnt vmcnt(0)" ::: "memory");
    }
    __builtin_amdgcn_s_barrier();                        // strip g visible to all waves

    const uint16_t* bufp = sB[g&1];
    if (g == 0)      mma(bufp, rg, afr);                 // r += agg@W1r
    else if (g == 1){
      mma(bufp, rg, hfr);                                // r += h@W2r
      #pragma unroll
      for (int nf=0; nf<8; ++nf){
        int col = nf*16 + l15;
        float bs = bih[col] + bhh[col];
        #pragma unroll
        for (int i=0; i<4; ++i) rg[nf][i] = sigmf(rg[nf][i] + bs);
      }
    }
    else if (g == 2){
      mma(bufp, nn, hfr);                                // nn = h@W2n
      #pragma unroll
      for (int nf=0; nf<8; ++nf){
        int col = nf*16 + l15;
        float bin = bih[256+col], bhn = bhh[256+col];
        #pragma unroll
        for (int i=0; i<4; ++i)
          nn[nf][i] = bin + rg[nf][i]*(nn[nf][i] + bhn); // pre-accumulate form
        rg[nf] = vzero();                                // rg reused as z accumulator
      }
    }
    else if (g == 3){
      mma(bufp, nn, afr);                                // nn += agg@W1n
      #pragma unroll
      for (int nf=0; nf<8; ++nf)
        #pragma unroll
        for (int i=0; i<4; ++i) nn[nf][i] = tanhx(nn[nf][i]);
    }
    else if (g == 4) mma(bufp, rg, afr);                 // z += agg@W1z
    else             mma(bufp, rg, hfr);                 // z += h@W2z

    __builtin_amdgcn_s_barrier();                        // all waves done reading buf g&1
  }

  // ---- combine + direct C-layout writeout (in-place safe: own rows only) ----
  #pragma unroll
  for (int nf=0; nf<8; ++nf){
    int col = nf*16 + l15;
    float bs = bih[128+col] + bhh[128+col];
    #pragma unroll
    for (int i=0; i<4; ++i){
      int row = rbase + wave*16 + quad*4 + i;
      if (row < n){
        float z = sigmf(rg[nf][i] + bs);
        float hv = bf2f(h_in[(long)row*128 + col]);
        float hnew = nn[nf][i] + z*(hv - nn[nf][i]);
        h_out[(long)row*128 + col] = f2bf(hnew);
      }
    }
  }
}

// ---------------- reduce final per-type h into messages ----------------
__global__ void reduce_kernel(const uint16_t* __restrict__ hfin, float* __restrict__ messages,
                              long stride, int nt, int accumulate, int total8){
  int i = blockIdx.x*256 + threadIdx.x;   // units of 8 elements
  if (i < total8){
    float acc[8];
    #pragma unroll
    for (int j=0;j<8;++j) acc[j] = 0.f;
    if (accumulate){
      #pragma unroll
      for (int j=0;j<8;++j) acc[j] = messages[(long)i*8 + j];
    }
    for (int t=0; t<nt; ++t){
      short8 v = *(const short8*)(hfin + (long)t*stride + (long)i*8);
      #pragma unroll
      for (int j=0;j<8;++j) acc[j] += bf2f((uint16_t)v[j]);
    }
    #pragma unroll
    for (int j=0;j<8;++j) messages[(long)i*8 + j] = acc[j];
  }
}

// ---------------- pooling + classifier ----------------
__global__ void pool_kernel(const float* __restrict__ messages, const int* __restrict__ batch,
                            float* __restrict__ sums, int* __restrict__ cntg, int n){
  int id = blockIdx.x*256 + threadIdx.x;
  int col = id & 127;
  int nb = (id >> 7) * 8;
  float acc = 0.f; int curg = -1; int ccount = 0;
  for (int j=0; j<8; ++j){
    int node = nb + j;
    if (node < n){
      int g = batch[node];
      if (g != curg){
        if (curg >= 0){
          atomicAdd(&sums[curg*128+col], acc);
          if (col == 0) atomicAdd(&cntg[curg], ccount);
        }
        curg = g; acc = 0.f; ccount = 0;
      }
      acc += messages[(long)node*128 + col];
      ccount++;
    }
  }
  if (curg >= 0){
    atomicAdd(&sums[curg*128+col], acc);
    if (col == 0) atomicAdd(&cntg[curg], ccount);
  }
}

__global__ void classify_kernel(const float* __restrict__ sums, const int* __restrict__ cntg,
                                const float* __restrict__ cls_w, const float* __restrict__ cls_b,
                                float* __restrict__ out, int G){
  int g = threadIdx.x;
  if (g < G){
    float inv = 1.0f / fmaxf((float)cntg[g], 1.0f);
    float o0 = 0.f, o1 = 0.f;
    for (int d=0; d<128; ++d){
      float p = sums[g*128+d]*inv;
      o0 += p*cls_w[d*2];
      o1 += p*cls_w[d*2+1];
    }
    out[g*2]   = o0 + cls_b[0];
    out[g*2+1] = o1 + cls_b[1];
  }
}

extern "C" void kernel_launch(void* const* d_in, const int* in_sizes, int n_in,
                              void* d_out, int out_size, void* d_ws, size_t ws_size,
                              hipStream_t stream)
{
  const float* x      = (const float*)d_in[0];
  const int*   ei     = (const int*)d_in[1];
  const int*   ea     = (const int*)d_in[2];
  const int*   batch  = (const int*)d_in[3];
  const float* lin_w  = (const float*)d_in[4];
  const float* lin_b  = (const float*)d_in[5];
  const float* ggnn_w = (const float*)d_in[6];
  const float* w_ih   = (const float*)d_in[7];
  const float* w_hh   = (const float*)d_in[8];
  const float* b_ih   = (const float*)d_in[9];
  const float* b_hh   = (const float*)d_in[10];
  const float* cls_w  = (const float*)d_in[11];
  const float* cls_b  = (const float*)d_in[12];
  float* out = (float*)d_out;

  const int N = in_sizes[3];          // 50000 nodes
  const int E = in_sizes[2];          // 800000 edges
  const int T = in_sizes[9] / 384;    // 13 edge types
  const int G = out_size / 2;         // 256 graphs
  const int STEPS = 8;

  // ---- workspace: persistent block + overlap region (prep buffers alias hT/agg) ----
  struct Layout {
    float *messages, *sums; int *cntg, *total;
    int *cnt, *row_start, *csr;
    uint16_t *W2t, *W1t, *h0;
    uint16_t *hT, *agg;
    int *cursor; uint16_t *xb, *lwT, *gwb, *wihb;
    size_t zero_off, zero_len, end;
  };
  auto make_layout = [&](int nh)->Layout{
    Layout L; char* base = (char*)d_ws; char* p = base;
    auto A = [&](size_t b)->char*{ char* r = p; p += (b + 255) & ~(size_t)255; return r; };
    L.messages  = (float*)A((size_t)N*128*4);
    char* z0 = p;
    L.sums      = (float*)A((size_t)G*128*4);
    L.cntg      = (int*)  A((size_t)G*4);
    L.total     = (int*)  A(256);
    L.zero_off = (size_t)(z0 - base); L.zero_len = (size_t)(p - z0);
    L.cnt       = (int*)  A((size_t)T*N*4);
    L.row_start = (int*)  A((size_t)T*N*4);
    L.csr       = (int*)  A((size_t)E*4);
    L.W2t       = (uint16_t*)A((size_t)T*384*128*2);
    L.W1t       = (uint16_t*)A((size_t)T*8*384*128*2);
    L.h0        = (uint16_t*)A((size_t)N*128*2);
    // overlap region: [hT | agg] || prep-only buffers
    char* R = p;
    size_t hb  = (size_t)N*128*2;
    size_t hba = ((size_t)nh*hb + 255) & ~(size_t)255;
    L.hT = (uint16_t*)R; L.agg = (uint16_t*)(R + hba);
    size_t hreg = 2*hba;
    char* q = R;
    auto B = [&](size_t b)->char*{ char* r = q; q += (b + 255) & ~(size_t)255; return r; };
    L.cursor = (int*)     B((size_t)T*N*4);
    L.xb     = (uint16_t*)B((size_t)N*384*2);
    L.lwT    = (uint16_t*)B((size_t)128*384*2);
    L.gwb    = (uint16_t*)B((size_t)T*8*128*128*2);
    L.wihb   = (uint16_t*)B((size_t)T*384*128*2);
    size_t preg = (size_t)(q - R);
    L.end = (size_t)(R - base) + (hreg > preg ? hreg : preg);
    return L;
  };
  // in-place h: working set 2*nh*12.8 MB; nh=7 -> ~179 MB + weights, L3-resident
  int nh = 1;
  { int cand[6] = {7, 6, 5, 4, 3, 2};
    for (int i=0; i<6; ++i){
      int c = cand[i] < T ? cand[i] : T;
      if (make_layout(c).end <= ws_size){ nh = c; break; }
    } }
  Layout L = make_layout(nh);

  hipMemsetAsync((char*)d_ws + L.zero_off, 0, L.zero_len, stream);   // sums/cntg/total
  hipMemsetAsync(L.cnt, 0, (size_t)T*N*4, stream);

  const int ngw = T*8*128*128, nwih = T*384*128;
  cast_bf16_kernel<<<(ngw+255)/256, 256, 0, stream>>>(ggnn_w, L.gwb, ngw);
  cast_bf16_kernel<<<(nwih+255)/256, 256, 0, stream>>>(w_ih, L.wihb, nwih);
  cast_swz_kernel <<<(nwih+255)/256, 256, 0, stream>>>(w_hh, L.W2t, nwih);
  xpad_kernel<<<((N*384)+255)/256, 256, 0, stream>>>(x, L.xb, N);
  lwt_kernel<<<(128*384+255)/256, 256, 0, stream>>>(lin_w, L.lwT);

  // W1t[t*8+s][j][k] = sum_d w_ih[t][j][d] * ggnn_w[t][s][k][d]  (swizzled store)
  gemm_bt_kernel<<<dim3(6, T*8), 256, 0, stream>>>(L.wihb, L.gwb, L.W1t, 128, 128, 384, 4,
      nullptr, 1, (long)384*128, (long)128*128, (long)384*128, 8);
  // h0 = xb @ lwT^T + lin_b   (plain store)
  gemm_bt_kernel<<<dim3((N+63)/64, 1), 256, 0, stream>>>(L.xb, L.lwT, L.h0, 384, 384, N, 12,
      lin_b, 0, 0, 0, 0, 1);

  edge_count_kernel<<<(E+255)/256, 256, 0, stream>>>(ei, ea, L.cnt, E, N);
  csr_alloc_kernel <<<(T*N+255)/256, 256, 0, stream>>>(L.cnt, L.row_start, L.cursor, L.total, T*N);
  edge_fill_kernel <<<(E+255)/256, 256, 0, stream>>>(ei, ea, L.cursor, L.csr, E, N);

  const int nblk = (N+127)/128;
  const int ablk = (N*16 + 255)/256;
  const long hs = (long)N*128;
  const int total8 = N*128/8;
  const int ngroups = (T + nh - 1)/nh;

  for (int gidx=0; gidx<ngroups; ++gidx){
    int t0 = gidx*nh, nt = (T - t0 < nh) ? (T - t0) : nh;
    for (int s=0; s<STEPS; ++s){
      const uint16_t* hin = (s==0) ? L.h0 : L.hT;
      long hin_stride = (s==0) ? 0 : hs;
      // Pass A: gather into agg (bandwidth-bound, high occupancy)
      agg_kernel<<<dim3(ablk, nt), 256, 0, stream>>>(
          hin, L.agg, L.row_start, L.cnt, L.csr, N, t0, hin_stride);
      // Pass B: dense dual-GEMM + GRU; writes hT (in place for s>=1)
      ggnn_step_kernel<<<dim3(nblk, nt), 512, 0, stream>>>(
          hin, L.agg, L.hT, L.W1t, L.W2t, b_ih, b_hh,
          N, s, t0, hin_stride, hs);
    }
    // fold this group's final h into messages
    reduce_kernel<<<(total8+255)/256, 256, 0, stream>>>(L.hT, L.messages, hs, nt,
                                                        (gidx>0) ? 1 : 0, total8);
  }

  pool_kernel<<<((N*128)+2047)/2048, 256, 0, stream>>>(L.messages, batch, L.sums, L.cntg, N);
  classify_kernel<<<1, 256, 0, stream>>>(L.sums, L.cntg, cls_w, cls_b, out, G);
}

// Round 10
// 3139.897 us; speedup vs baseline: 1.2224x; 1.0366x over previous
//
#include <hip/hip_runtime.h>
#include <hip/hip_bf16.h>
#include <stdint.h>

typedef __attribute__((ext_vector_type(8))) short   short8;
typedef __attribute__((ext_vector_type(8))) __bf16  bf16x8;
typedef __attribute__((ext_vector_type(4))) float   f32x4;

#define DEV __device__ __forceinline__

DEV float bf2f(uint16_t u){ union{uint32_t i; float f;} v; v.i = ((uint32_t)u)<<16; return v.f; }
DEV uint16_t f2bf(float f){
  union{ __hip_bfloat16 b; uint16_t u; } v; v.b = __float2bfloat16(f); return v.u;  // hw cvt, RNE
}
DEV float sigmf(float x){ return 1.0f/(1.0f + __expf(-x)); }
DEV float tanhx(float x){ x = fminf(15.f, fmaxf(-15.f, x)); float e = __expf(-2.0f*x);
  return (1.0f-e)/(1.0f+e); }

DEV bf16x8 as_bf(short8 s){ union{ short8 s; bf16x8 b; } u; u.s = s; return u.b; }
DEV f32x4 mfma16(short8 a, short8 b, f32x4 c){
  return __builtin_amdgcn_mfma_f32_16x16x32_bf16(as_bf(a), as_bf(b), c, 0, 0, 0);
}
DEV f32x4 vzero(){ f32x4 v; v[0]=0.f; v[1]=0.f; v[2]=0.f; v[3]=0.f; return v; }

// async global->LDS, 16B per lane (dest = wave-uniform base + lane*16)
DEV void gload16(const uint16_t* g, uint16_t* l){
  __builtin_amdgcn_global_load_lds((const __attribute__((address_space(1))) void*)g,
                                   (__attribute__((address_space(3))) void*)l, 16, 0, 0);
}

// ---------------- small prep kernels ----------------
__global__ void cast_bf16_kernel(const float* __restrict__ in, uint16_t* __restrict__ out, int n){
  int i = blockIdx.x*256 + threadIdx.x;
  if (i < n) out[i] = f2bf(in[i]);
}

// rows of 128, store with XOR-swizzled 16B chunks (matches LDS strip layout)
__global__ void cast_swz_kernel(const float* __restrict__ in, uint16_t* __restrict__ out, int n){
  int i = blockIdx.x*256 + threadIdx.x;
  if (i < n){
    int k = i & 127, row = i >> 7;
    out[(row<<7) + (((k>>3) ^ (row&15))<<3) + (k&7)] = f2bf(in[i]);
  }
}

__global__ void xpad_kernel(const float* __restrict__ x, uint16_t* __restrict__ xb, int rows){
  int i = blockIdx.x*256 + threadIdx.x;
  if (i < rows*384){
    int r = i/384, c = i - r*384;
    xb[i] = (c < 369) ? f2bf(x[r*369 + c]) : (uint16_t)0;
  }
}

__global__ void lwt_kernel(const float* __restrict__ lw, uint16_t* __restrict__ lwT){
  int i = blockIdx.x*256 + threadIdx.x;   // out [128][384]: lwT[n][k] = lin_w[k][n]
  if (i < 128*384){
    int nn = i/384, k = i - nn*384;
    lwT[i] = (k < 369) ? f2bf(lw[k*128 + nn]) : (uint16_t)0;
  }
}

// ---------------- generic bf16 gemm: C[m][n] = sum_k A[m][k]*B[n][k] (+bias[n]) ----------------
__global__ __launch_bounds__(256,2)
void gemm_bt_kernel(const uint16_t* __restrict__ A, const uint16_t* __restrict__ B,
                    uint16_t* __restrict__ C,
                    int lda, int ldb, int M, int K4,
                    const float* __restrict__ bias, int swz,
                    long sA, long sB, long sC, int divA)
{
  int by = blockIdx.y;
  A += (long)(by/divA)*sA; B += (long)by*sB; C += (long)by*sC;
  int tid = threadIdx.x, lane = tid&63, wave = tid>>6;
  int l15 = lane&15, quad = lane>>4;
  int m0 = blockIdx.x*64 + wave*16;
  f32x4 acc[8];
  #pragma unroll
  for (int nf=0; nf<8; ++nf) acc[nf] = vzero();
  int mrow = min(m0 + l15, M-1);
  const char* arow = (const char*)(A + (long)mrow*lda) + quad*16;
  for (int kk=0; kk<K4; ++kk){
    short8 a = *(const short8*)(arow + kk*64);
    #pragma unroll
    for (int nf=0; nf<8; ++nf){
      const char* brow = (const char*)(B + (long)(nf*16+l15)*ldb) + quad*16;
      short8 b = *(const short8*)(brow + kk*64);
      acc[nf] = mfma16(a, b, acc[nf]);
    }
  }
  #pragma unroll
  for (int nf=0; nf<8; ++nf){
    int col = nf*16 + l15;
    float bb = bias ? bias[col] : 0.0f;
    #pragma unroll
    for (int i=0; i<4; ++i){
      int row = m0 + quad*4 + i;
      if (row < M){
        float v = acc[nf][i] + bb;
        int idx = swz ? (row*128 + (((col>>3)^(row&15))<<3) + (col&7)) : (row*128+col);
        C[idx] = f2bf(v);
      }
    }
  }
}

// ---------------- CSR build ----------------
__global__ void edge_count_kernel(const int* __restrict__ ei, const int* __restrict__ ea,
                                  int* __restrict__ cnt, int E, int n){
  int e = blockIdx.x*256 + threadIdx.x;
  if (e < E){
    int dst = ei[E + e];
    int t = ea[e];
    atomicAdd(&cnt[t*n + dst], 1);
  }
}

__global__ void csr_alloc_kernel(const int* __restrict__ cnt, int* __restrict__ row_start,
                                 int* __restrict__ cursor, int* __restrict__ total, int R){
  __shared__ int wsum[4];
  __shared__ int base;
  int i = blockIdx.x*256 + threadIdx.x;
  int c = (i < R) ? cnt[i] : 0;
  int lane = threadIdx.x & 63, wave = threadIdx.x >> 6;
  int x = c;
  #pragma unroll
  for (int d=1; d<64; d<<=1){ int y = __shfl_up(x, d, 64); if (lane >= d) x += y; }
  if (lane == 63) wsum[wave] = x;
  __syncthreads();
  if (threadIdx.x == 0){
    int s0=wsum[0], s1=wsum[1], s2=wsum[2], s3=wsum[3];
    base = atomicAdd(total, s0+s1+s2+s3);
    wsum[0]=0; wsum[1]=s0; wsum[2]=s0+s1; wsum[3]=s0+s1+s2;
  }
  __syncthreads();
  int st = base + wsum[wave] + (x - c);
  if (i < R){ row_start[i] = st; cursor[i] = st; }
}

__global__ void edge_fill_kernel(const int* __restrict__ ei, const int* __restrict__ ea,
                                 int* __restrict__ cursor, int* __restrict__ csr, int E, int n){
  int e = blockIdx.x*256 + threadIdx.x;
  if (e < E){
    int src = ei[e], dst = ei[E+e], t = ea[e];
    int pos = atomicAdd(&cursor[t*n + dst], 1);
    csr[pos] = src;
  }
}

// ---------------- Pass A: aggregation (pure gather, high occupancy) ----------------
// thread = (row, 8-col chunk); 16 threads cover a 128-col row (256B coalesced per edge)
__global__ void agg_kernel(const uint16_t* __restrict__ h_in_b,
                           uint16_t* __restrict__ agg_b,
                           const int* __restrict__ row_start_b,
                           const int* __restrict__ row_cnt_b,
                           const int* __restrict__ csr_src,
                           int n, int t_off, long hin_stride)
{
  const int t = t_off + blockIdx.y;
  const uint16_t* h_in = h_in_b + (long)blockIdx.y*hin_stride;
  uint16_t* agg = agg_b + (long)blockIdx.y*((long)n*128);
  int id = blockIdx.x*256 + threadIdx.x;
  int row = id >> 4, c = (id & 15) * 8;
  if (row < n){
    int st = row_start_b[(size_t)t*n + row];
    int cn = row_cnt_b  [(size_t)t*n + row];
    float acc[8] = {0,0,0,0,0,0,0,0};
    for (int e=0; e<cn; ++e){
      int src = csr_src[st + e];
      short8 v = *(const short8*)(h_in + (long)src*128 + c);
      #pragma unroll
      for (int j=0; j<8; ++j) acc[j] += bf2f((uint16_t)v[j]);
    }
    short8 pk;
    #pragma unroll
    for (int j=0; j<8; ++j) pk[j] = (short)f2bf(acc[j]);
    *(short8*)(agg + (long)row*128 + c) = pk;
  }
}

// ---------------- Pass B: dense GEMM + GRU (v5 = R9 + 1-barrier strips + setprio) ----------------
// Block = 128 rows x 128 cols of one edge-type; 512 thr / 8 waves; 2 blocks/CU (64 KB LDS).
// Data layout/epilogue byte-identical to R9 (reproducible 3255us; 141/122 MB traffic).
// Schedule: catalog T3 minimum-2-phase — ONE vmcnt(0)+barrier per strip (was 2 barriers +
// counted vmcnt). Per strip: {wait own DMA; barrier (publishes strip g AND proves all waves
// done reading buf !(g&1)); issue DMA(g+1) into buf !(g&1); mma(g)}. DMA(g+1) flies under
// mma(g). T5: setprio(1) around the MFMA cluster (2 blocks/CU at different phases -> the
// scheduler has roles to arbitrate). ZERO added registers (R8 lesson: any extra live state
// spills and flips the traffic mode). In-place safe: block touches only its own rows.
__global__ __launch_bounds__(512, 4)
void ggnn_step_kernel(const uint16_t* __restrict__ h_in_b,
                      const uint16_t* __restrict__ agg_b,
                      uint16_t* __restrict__ h_out_b,
                      const uint16_t* __restrict__ W1_b,   // [T*8][384][128] swizzled
                      const uint16_t* __restrict__ W2_b,   // [T][384][128] swizzled
                      const float* __restrict__ bih_b,     // [T][384]
                      const float* __restrict__ bhh_b,     // [T][384]
                      int n, int s, int t_off,
                      long hin_stride, long hstride)
{
  __shared__ __align__(16) uint16_t sB[2][128*128];    // 2 x 32 KB strips
  const int t = t_off + blockIdx.y;
  const uint16_t* h_in = h_in_b + (long)blockIdx.y*hin_stride;
  const uint16_t* agg  = agg_b  + (long)blockIdx.y*hstride;
  uint16_t*       h_out= h_out_b+ (long)blockIdx.y*hstride;
  const uint16_t* W1s = W1_b + (size_t)(t*8+s)*384*128;
  const uint16_t* W2s = W2_b + (size_t)t*384*128;
  const float* bih = bih_b + t*384;
  const float* bhh = bhh_b + t*384;

  const int tid = threadIdx.x, lane = tid&63, wave = tid>>6;   // 8 waves
  const int l15 = lane&15, quad = lane>>4;
  const int rbase = blockIdx.x*128;

  // strips in use order: rW1, rW2, nW2, nW1, zW1, zW2 (torch rows: r=0..127, z=128..255, n=256..383)
  const uint16_t* stp[6] = { W1s, W2s, W2s+2*16384, W1s+2*16384, W1s+16384, W2s+16384 };

  // ---- stage strip 0 into buf 0 (DMA; 512 thr x 16B x 4 rounds = 32KB) ----
  {
    const uint16_t* gp = stp[0] + tid*8;
    uint16_t* lp = &sB[0][tid*8];
    #pragma unroll
    for (int it=0; it<4; ++it) gload16(gp + it*4096, lp + it*4096);
  }

  // ---- A-fragments: h (used 3x) and agg (used 3x) ----
  const int ar = min(rbase + wave*16 + l15, n-1);
  short8 hfr[4], afr[4];
  {
    const short8* hrow = (const short8*)(h_in + (long)ar*128);
    const short8* arow = (const short8*)(agg  + (long)ar*128);
    #pragma unroll
    for (int kk=0; kk<4; ++kk){ hfr[kk] = hrow[kk*4 + quad]; afr[kk] = arow[kk*4 + quad]; }
  }

  auto mma = [&](const uint16_t* bufp, f32x4 (&acc)[8], const short8 (&frag)[4]){
    __builtin_amdgcn_s_setprio(1);
    #pragma unroll
    for (int kk=0; kk<4; ++kk){
      const int ch = ((kk*4+quad)^l15)<<4;
      short8 a = frag[kk];
      #pragma unroll
      for (int nf=0; nf<8; ++nf){
        short8 b = *(const short8*)((const char*)bufp + (nf*16+l15)*256 + ch);
        acc[nf] = mfma16(a, b, acc[nf]);
      }
    }
    __builtin_amdgcn_s_setprio(0);
  };

  f32x4 rg[8], nn[8];
  #pragma unroll
  for (int nf=0; nf<8; ++nf){ rg[nf]=vzero(); nn[nf]=vzero(); }

  // ---- 6 strips: one vmcnt(0)+barrier per strip; DMA(g+1) issued after barrier, flies
  //      under mma(g). Safety: barrier proves (a) every wave drained its own strip-g DMA
  //      (vmcnt(0) precedes it) => strip g fully in LDS; (b) every wave finished mma(g-1)
  //      on buf !(g&1) => DMA(g+1) may overwrite it. ----
  #pragma unroll
  for (int g=0; g<6; ++g){
    asm volatile("s_waitcnt vmcnt(0)" ::: "memory");   // own strip-g portion (and A-frags) landed
    __builtin_amdgcn_s_barrier();

    if (g < 5){
      const uint16_t* gp = stp[g+1] + tid*8;
      uint16_t* lp = &sB[(g+1)&1][tid*8];
      #pragma unroll
      for (int it=0; it<4; ++it) gload16(gp + it*4096, lp + it*4096);
      __builtin_amdgcn_sched_barrier(0);               // pin DMA issue before the mma phase
    }

    const uint16_t* bufp = sB[g&1];
    if (g == 0)      mma(bufp, rg, afr);                 // r += agg@W1r
    else if (g == 1){
      mma(bufp, rg, hfr);                                // r += h@W2r
      #pragma unroll
      for (int nf=0; nf<8; ++nf){
        int col = nf*16 + l15;
        float bs = bih[col] + bhh[col];
        #pragma unroll
        for (int i=0; i<4; ++i) rg[nf][i] = sigmf(rg[nf][i] + bs);
      }
    }
    else if (g == 2){
      mma(bufp, nn, hfr);                                // nn = h@W2n
      #pragma unroll
      for (int nf=0; nf<8; ++nf){
        int col = nf*16 + l15;
        float bin = bih[256+col], bhn = bhh[256+col];
        #pragma unroll
        for (int i=0; i<4; ++i)
          nn[nf][i] = bin + rg[nf][i]*(nn[nf][i] + bhn); // pre-accumulate form
        rg[nf] = vzero();                                // rg reused as z accumulator
      }
    }
    else if (g == 3){
      mma(bufp, nn, afr);                                // nn += agg@W1n
      #pragma unroll
      for (int nf=0; nf<8; ++nf)
        #pragma unroll
        for (int i=0; i<4; ++i) nn[nf][i] = tanhx(nn[nf][i]);
    }
    else if (g == 4) mma(bufp, rg, afr);                 // z += agg@W1z
    else             mma(bufp, rg, hfr);                 // z += h@W2z
  }

  // ---- combine + direct C-layout writeout (in-place safe: own rows only) ----
  #pragma unroll
  for (int nf=0; nf<8; ++nf){
    int col = nf*16 + l15;
    float bs = bih[128+col] + bhh[128+col];
    #pragma unroll
    for (int i=0; i<4; ++i){
      int row = rbase + wave*16 + quad*4 + i;
      if (row < n){
        float z = sigmf(rg[nf][i] + bs);
        float hv = bf2f(h_in[(long)row*128 + col]);
        float hnew = nn[nf][i] + z*(hv - nn[nf][i]);
        h_out[(long)row*128 + col] = f2bf(hnew);
      }
    }
  }
}

// ---------------- reduce final per-type h into messages ----------------
__global__ void reduce_kernel(const uint16_t* __restrict__ hfin, float* __restrict__ messages,
                              long stride, int nt, int accumulate, int total8){
  int i = blockIdx.x*256 + threadIdx.x;   // units of 8 elements
  if (i < total8){
    float acc[8];
    #pragma unroll
    for (int j=0;j<8;++j) acc[j] = 0.f;
    if (accumulate){
      #pragma unroll
      for (int j=0;j<8;++j) acc[j] = messages[(long)i*8 + j];
    }
    for (int t=0; t<nt; ++t){
      short8 v = *(const short8*)(hfin + (long)t*stride + (long)i*8);
      #pragma unroll
      for (int j=0;j<8;++j) acc[j] += bf2f((uint16_t)v[j]);
    }
    #pragma unroll
    for (int j=0;j<8;++j) messages[(long)i*8 + j] = acc[j];
  }
}

// ---------------- pooling + classifier ----------------
__global__ void pool_kernel(const float* __restrict__ messages, const int* __restrict__ batch,
                            float* __restrict__ sums, int* __restrict__ cntg, int n){
  int id = blockIdx.x*256 + threadIdx.x;
  int col = id & 127;
  int nb = (id >> 7) * 8;
  float acc = 0.f; int curg = -1; int ccount = 0;
  for (int j=0; j<8; ++j){
    int node = nb + j;
    if (node < n){
      int g = batch[node];
      if (g != curg){
        if (curg >= 0){
          atomicAdd(&sums[curg*128+col], acc);
          if (col == 0) atomicAdd(&cntg[curg], ccount);
        }
        curg = g; acc = 0.f; ccount = 0;
      }
      acc += messages[(long)node*128 + col];
      ccount++;
    }
  }
  if (curg >= 0){
    atomicAdd(&sums[curg*128+col], acc);
    if (col == 0) atomicAdd(&cntg[curg], ccount);
  }
}

__global__ void classify_kernel(const float* __restrict__ sums, const int* __restrict__ cntg,
                                const float* __restrict__ cls_w, const float* __restrict__ cls_b,
                                float* __restrict__ out, int G){
  int g = threadIdx.x;
  if (g < G){
    float inv = 1.0f / fmaxf((float)cntg[g], 1.0f);
    float o0 = 0.f, o1 = 0.f;
    for (int d=0; d<128; ++d){
      float p = sums[g*128+d]*inv;
      o0 += p*cls_w[d*2];
      o1 += p*cls_w[d*2+1];
    }
    out[g*2]   = o0 + cls_b[0];
    out[g*2+1] = o1 + cls_b[1];
  }
}

extern "C" void kernel_launch(void* const* d_in, const int* in_sizes, int n_in,
                              void* d_out, int out_size, void* d_ws, size_t ws_size,
                              hipStream_t stream)
{
  const float* x      = (const float*)d_in[0];
  const int*   ei     = (const int*)d_in[1];
  const int*   ea     = (const int*)d_in[2];
  const int*   batch  = (const int*)d_in[3];
  const float* lin_w  = (const float*)d_in[4];
  const float* lin_b  = (const float*)d_in[5];
  const float* ggnn_w = (const float*)d_in[6];
  const float* w_ih   = (const float*)d_in[7];
  const float* w_hh   = (const float*)d_in[8];
  const float* b_ih   = (const float*)d_in[9];
  const float* b_hh   = (const float*)d_in[10];
  const float* cls_w  = (const float*)d_in[11];
  const float* cls_b  = (const float*)d_in[12];
  float* out = (float*)d_out;

  const int N = in_sizes[3];          // 50000 nodes
  const int E = in_sizes[2];          // 800000 edges
  const int T = in_sizes[9] / 384;    // 13 edge types
  const int G = out_size / 2;         // 256 graphs
  const int STEPS = 8;

  // ---- workspace: persistent block + overlap region (prep buffers alias hT/agg) ----
  struct Layout {
    float *messages, *sums; int *cntg, *total;
    int *cnt, *row_start, *csr;
    uint16_t *W2t, *W1t, *h0;
    uint16_t *hT, *agg;
    int *cursor; uint16_t *xb, *lwT, *gwb, *wihb;
    size_t zero_off, zero_len, end;
  };
  auto make_layout = [&](int nh)->Layout{
    Layout L; char* base = (char*)d_ws; char* p = base;
    auto A = [&](size_t b)->char*{ char* r = p; p += (b + 255) & ~(size_t)255; return r; };
    L.messages  = (float*)A((size_t)N*128*4);
    char* z0 = p;
    L.sums      = (float*)A((size_t)G*128*4);
    L.cntg      = (int*)  A((size_t)G*4);
    L.total     = (int*)  A(256);
    L.zero_off = (size_t)(z0 - base); L.zero_len = (size_t)(p - z0);
    L.cnt       = (int*)  A((size_t)T*N*4);
    L.row_start = (int*)  A((size_t)T*N*4);
    L.csr       = (int*)  A((size_t)E*4);
    L.W2t       = (uint16_t*)A((size_t)T*384*128*2);
    L.W1t       = (uint16_t*)A((size_t)T*8*384*128*2);
    L.h0        = (uint16_t*)A((size_t)N*128*2);
    // overlap region: [hT | agg] || prep-only buffers
    char* R = p;
    size_t hb  = (size_t)N*128*2;
    size_t hba = ((size_t)nh*hb + 255) & ~(size_t)255;
    L.hT = (uint16_t*)R; L.agg = (uint16_t*)(R + hba);
    size_t hreg = 2*hba;
    char* q = R;
    auto B = [&](size_t b)->char*{ char* r = q; q += (b + 255) & ~(size_t)255; return r; };
    L.cursor = (int*)     B((size_t)T*N*4);
    L.xb     = (uint16_t*)B((size_t)N*384*2);
    L.lwT    = (uint16_t*)B((size_t)128*384*2);
    L.gwb    = (uint16_t*)B((size_t)T*8*128*128*2);
    L.wihb   = (uint16_t*)B((size_t)T*384*128*2);
    size_t preg = (size_t)(q - R);
    L.end = (size_t)(R - base) + (hreg > preg ? hreg : preg);
    return L;
  };
  // in-place h: working set 2*nh*12.8 MB; nh=7 -> ~179 MB + weights, L3-resident
  int nh = 1;
  { int cand[6] = {7, 6, 5, 4, 3, 2};
    for (int i=0; i<6; ++i){
      int c = cand[i] < T ? cand[i] : T;
      if (make_layout(c).end <= ws_size){ nh = c; break; }
    } }
  Layout L = make_layout(nh);

  hipMemsetAsync((char*)d_ws + L.zero_off, 0, L.zero_len, stream);   // sums/cntg/total
  hipMemsetAsync(L.cnt, 0, (size_t)T*N*4, stream);

  const int ngw = T*8*128*128, nwih = T*384*128;
  cast_bf16_kernel<<<(ngw+255)/256, 256, 0, stream>>>(ggnn_w, L.gwb, ngw);
  cast_bf16_kernel<<<(nwih+255)/256, 256, 0, stream>>>(w_ih, L.wihb, nwih);
  cast_swz_kernel <<<(nwih+255)/256, 256, 0, stream>>>(w_hh, L.W2t, nwih);
  xpad_kernel<<<((N*384)+255)/256, 256, 0, stream>>>(x, L.xb, N);
  lwt_kernel<<<(128*384+255)/256, 256, 0, stream>>>(lin_w, L.lwT);

  // W1t[t*8+s][j][k] = sum_d w_ih[t][j][d] * ggnn_w[t][s][k][d]  (swizzled store)
  gemm_bt_kernel<<<dim3(6, T*8), 256, 0, stream>>>(L.wihb, L.gwb, L.W1t, 128, 128, 384, 4,
      nullptr, 1, (long)384*128, (long)128*128, (long)384*128, 8);
  // h0 = xb @ lwT^T + lin_b   (plain store)
  gemm_bt_kernel<<<dim3((N+63)/64, 1), 256, 0, stream>>>(L.xb, L.lwT, L.h0, 384, 384, N, 12,
      lin_b, 0, 0, 0, 0, 1);

  edge_count_kernel<<<(E+255)/256, 256, 0, stream>>>(ei, ea, L.cnt, E, N);
  csr_alloc_kernel <<<(T*N+255)/256, 256, 0, stream>>>(L.cnt, L.row_start, L.cursor, L.total, T*N);
  edge_fill_kernel <<<(E+255)/256, 256, 0, stream>>>(ei, ea, L.cursor, L.csr, E, N);

  const int nblk = (N+127)/128;
  const int ablk = (N*16 + 255)/256;
  const long hs = (long)N*128;
  const int total8 = N*128/8;
  const int ngroups = (T + nh - 1)/nh;

  for (int gidx=0; gidx<ngroups; ++gidx){
    int t0 = gidx*nh, nt = (T - t0 < nh) ? (T - t0) : nh;
    for (int s=0; s<STEPS; ++s){
      const uint16_t* hin = (s==0) ? L.h0 : L.hT;
      long hin_stride = (s==0) ? 0 : hs;
      // Pass A: gather into agg (bandwidth-bound, high occupancy)
      agg_kernel<<<dim3(ablk, nt), 256, 0, stream>>>(
          hin, L.agg, L.row_start, L.cnt, L.csr, N, t0, hin_stride);
      // Pass B: dense dual-GEMM + GRU; writes hT (in place for s>=1)
      ggnn_step_kernel<<<dim3(nblk, nt), 512, 0, stream>>>(
          hin, L.agg, L.hT, L.W1t, L.W2t, b_ih, b_hh,
          N, s, t0, hin_stride, hs);
    }
    // fold this group's final h into messages
    reduce_kernel<<<(total8+255)/256, 256, 0, stream>>>(L.hT, L.messages, hs, nt,
                                                        (gidx>0) ? 1 : 0, total8);
  }

  pool_kernel<<<((N*128)+2047)/2048, 256, 0, stream>>>(L.messages, batch, L.sums, L.cntg, N);
  classify_kernel<<<1, 256, 0, stream>>>(L.sums, L.cntg, cls_w, cls_b, out, G);
}